// Round 2
// baseline (1331.562 us; speedup 1.0000x reference)
//
#include <hip/hip_runtime.h>
#include <math.h>

// ---------------- degree / norm ----------------
__global__ void k_degree(const int* __restrict__ dst, int E, int* __restrict__ cnt) {
    int i = blockIdx.x * 256 + threadIdx.x;
    if (i < E) atomicAdd(&cnt[dst[i]], 1);
}

__global__ void k_dinv(const int* __restrict__ cnt, float* __restrict__ dinv, int N) {
    int i = blockIdx.x * 256 + threadIdx.x;
    if (i < N) dinv[i] = rsqrtf((float)(cnt[i] + 1));  // +1 self loop
}

// ---------------- scan for CSR row_ptr ----------------
__global__ __launch_bounds__(512) void k_scan1(const int* __restrict__ cnt, int* __restrict__ rp,
                                               int* __restrict__ partials, int N) {
    __shared__ int s[512];
    int i = blockIdx.x * 512 + threadIdx.x;
    int v = (i < N) ? cnt[i] : 0;
    s[threadIdx.x] = v;
    __syncthreads();
    for (int d = 1; d < 512; d <<= 1) {
        int t = (threadIdx.x >= d) ? s[threadIdx.x - d] : 0;
        __syncthreads();
        s[threadIdx.x] += t;
        __syncthreads();
    }
    if (i < N) rp[i] = s[threadIdx.x] - v;  // exclusive within block
    if (threadIdx.x == 511) partials[blockIdx.x] = s[511];
}

__global__ void k_scan2(int* __restrict__ partials, int nb) {
    if (threadIdx.x == 0 && blockIdx.x == 0) {
        int acc = 0;
        for (int i = 0; i < nb; i++) { int v = partials[i]; partials[i] = acc; acc += v; }
    }
}

__global__ __launch_bounds__(512) void k_scan3(int* __restrict__ rp, const int* __restrict__ partials,
                                               int N, int E) {
    int i = blockIdx.x * 512 + threadIdx.x;
    if (i < N) rp[i] += partials[blockIdx.x];
    if (i == 0) rp[N] = E;
}

__global__ void k_fill(const int* __restrict__ src, const int* __restrict__ dst, int E,
                       const int* __restrict__ rp, int* __restrict__ cursor, int* __restrict__ col) {
    int i = blockIdx.x * 256 + threadIdx.x;
    if (i < E) {
        int d = dst[i];
        int pos = rp[d] + atomicAdd(&cursor[d], 1);
        col[pos] = src[i];
    }
}

// ---------------- GEMM1: h = x @ W1  (N x 512 @ 512 x 128, fp32) ----------------
__global__ __launch_bounds__(256) void k_gemm1(const float* __restrict__ x, const float* __restrict__ W,
                                               float* __restrict__ h, int N) {
    __shared__ float xs[64][36];     // 64 rows x 32 k, pad to 36
    __shared__ float ws[32][128];    // 32 k x 128 cols
    int tid = threadIdx.x;
    int n0 = blockIdx.x * 64;
    int tx = tid & 15, ty = tid >> 4;       // tx: col group (8 cols), ty: row group (4 rows)
    float acc[4][8];
#pragma unroll
    for (int i = 0; i < 4; i++)
#pragma unroll
        for (int j = 0; j < 8; j++) acc[i][j] = 0.f;

    int lr = tid >> 3;   // 0..31 (x-tile row base)
    int lf = tid & 7;    // float4 index within 32-k row
    int wq = tid & 31;   // W col quad
    int wr = tid >> 5;   // 0..7

    for (int k0 = 0; k0 < 512; k0 += 32) {
#pragma unroll
        for (int t = 0; t < 2; t++) {
            int r = lr + 32 * t;
            int gr = n0 + r;
            float4 v = make_float4(0.f, 0.f, 0.f, 0.f);
            if (gr < N) v = *(const float4*)&x[(size_t)gr * 512 + k0 + lf * 4];
            *(float4*)&xs[r][lf * 4] = v;
        }
#pragma unroll
        for (int t = 0; t < 4; t++) {
            int r = wr + 8 * t;
            *(float4*)&ws[r][wq * 4] = *(const float4*)&W[(size_t)(k0 + r) * 128 + wq * 4];
        }
        __syncthreads();
#pragma unroll
        for (int kk = 0; kk < 32; kk += 4) {
            float4 av[4];
#pragma unroll
            for (int i = 0; i < 4; i++) av[i] = *(float4*)&xs[ty * 4 + i][kk];
#pragma unroll
            for (int u = 0; u < 4; u++) {
                float4 b0 = *(float4*)&ws[kk + u][tx * 8];
                float4 b1 = *(float4*)&ws[kk + u][tx * 8 + 4];
#pragma unroll
                for (int i = 0; i < 4; i++) {
                    float a = (&av[i].x)[u];
                    acc[i][0] = fmaf(a, b0.x, acc[i][0]);
                    acc[i][1] = fmaf(a, b0.y, acc[i][1]);
                    acc[i][2] = fmaf(a, b0.z, acc[i][2]);
                    acc[i][3] = fmaf(a, b0.w, acc[i][3]);
                    acc[i][4] = fmaf(a, b1.x, acc[i][4]);
                    acc[i][5] = fmaf(a, b1.y, acc[i][5]);
                    acc[i][6] = fmaf(a, b1.z, acc[i][6]);
                    acc[i][7] = fmaf(a, b1.w, acc[i][7]);
                }
            }
        }
        __syncthreads();
    }
#pragma unroll
    for (int i = 0; i < 4; i++) {
        int gr = n0 + ty * 4 + i;
        if (gr < N) {
            *(float4*)&h[(size_t)gr * 128 + tx * 8] =
                make_float4(acc[i][0], acc[i][1], acc[i][2], acc[i][3]);
            *(float4*)&h[(size_t)gr * 128 + tx * 8 + 4] =
                make_float4(acc[i][4], acc[i][5], acc[i][6], acc[i][7]);
        }
    }
}

// ---------------- aggregation: out[v] = sum_{c in N(v)} dinv[c]*dinv[v]*h[c] + dinv[v]^2*h[v]
// DIM = 128, one wave per node, lane covers features lane and lane+64.
template <bool RELU_BIAS>
__global__ __launch_bounds__(256) void k_agg(const float* __restrict__ h, const float* __restrict__ dinv,
                                             const int* __restrict__ rp, const int* __restrict__ col,
                                             const float* __restrict__ bias, float* __restrict__ outb, int N) {
    int wave = threadIdx.x >> 6, lane = threadIdx.x & 63;
    int v = blockIdx.x * 4 + wave;
    if (v >= N) return;
    float dv = dinv[v];
    float wself = dv * dv;
    float acc0 = h[(size_t)v * 128 + lane] * wself;
    float acc1 = h[(size_t)v * 128 + 64 + lane] * wself;
    int e0 = rp[v], e1 = rp[v + 1];
    for (int i = e0; i < e1; i++) {
        int c = col[i];
        float w = dinv[c] * dv;
        acc0 = fmaf(h[(size_t)c * 128 + lane], w, acc0);
        acc1 = fmaf(h[(size_t)c * 128 + 64 + lane], w, acc1);
    }
    if (RELU_BIAS) {
        acc0 = fmaxf(acc0 + bias[lane], 0.f);
        acc1 = fmaxf(acc1 + bias[64 + lane], 0.f);
    }
    outb[(size_t)v * 128 + lane] = acc0;
    outb[(size_t)v * 128 + 64 + lane] = acc1;
}

// ---------------- W2 transpose (128x100 -> 100x128 padded rows) ----------------
__global__ void k_transpose(const float* __restrict__ W2, float* __restrict__ W2T) {
    int i = blockIdx.x * 256 + threadIdx.x;
    if (i < 128 * 100) {
        int k = i / 100, c = i % 100;
        W2T[(size_t)c * 128 + k] = W2[i];
    }
}

// ---------------- fused: out = log_softmax(g2 @ W2 + b2), wave per node ----------------
__global__ __launch_bounds__(256) void k_out(const float* __restrict__ g2, const float* __restrict__ W2T,
                                             const float* __restrict__ b2, float* __restrict__ out, int N) {
    __shared__ float g2s[4][128];
    int wave = threadIdx.x >> 6, lane = threadIdx.x & 63;
    int v = blockIdx.x * 4 + wave;
    if (v >= N) return;
    // stage this node's 128-dim row into LDS (wave-private; same-wave DS ops are ordered)
    float4 t = *(const float4*)&g2[(size_t)v * 128 + (lane & 31) * 4];
    if (lane < 32) *(float4*)&g2s[wave][lane * 4] = t;
    bool hi = lane < 36;
    float acc0 = 0.f, acc1 = 0.f;
#pragma unroll 4
    for (int k = 0; k < 128; k += 4) {
        float4 a = *(float4*)&g2s[wave][k];
        float4 w0 = *(const float4*)&W2T[(size_t)lane * 128 + k];
        acc0 = fmaf(a.x, w0.x, acc0);
        acc0 = fmaf(a.y, w0.y, acc0);
        acc0 = fmaf(a.z, w0.z, acc0);
        acc0 = fmaf(a.w, w0.w, acc0);
        if (hi) {
            float4 w1 = *(const float4*)&W2T[(size_t)(lane + 64) * 128 + k];
            acc1 = fmaf(a.x, w1.x, acc1);
            acc1 = fmaf(a.y, w1.y, acc1);
            acc1 = fmaf(a.z, w1.z, acc1);
            acc1 = fmaf(a.w, w1.w, acc1);
        }
    }
    float l0 = acc0 + b2[lane];
    float l1 = hi ? acc1 + b2[64 + lane] : -INFINITY;
    float m = fmaxf(l0, l1);
    for (int d = 32; d > 0; d >>= 1) m = fmaxf(m, __shfl_xor(m, d, 64));
    float s = __expf(l0 - m) + (hi ? __expf(l1 - m) : 0.f);
    for (int d = 32; d > 0; d >>= 1) s += __shfl_xor(s, d, 64);
    float lse = m + __logf(s);
    out[(size_t)v * 100 + lane] = l0 - lse;
    if (hi) out[(size_t)v * 100 + 64 + lane] = l1 - lse;
}

extern "C" void kernel_launch(void* const* d_in, const int* in_sizes, int n_in,
                              void* d_out, int out_size, void* d_ws, size_t ws_size,
                              hipStream_t stream) {
    const float* x  = (const float*)d_in[0];
    const int*   ei = (const int*)d_in[1];   // int32! (JAX x64 disabled; harness: integer -> const int*)
    const float* W1 = (const float*)d_in[2];
    const float* b1 = (const float*)d_in[3];
    const float* W2 = (const float*)d_in[4];
    const float* b2 = (const float*)d_in[5];
    float* out = (float*)d_out;

    int N = in_sizes[0] / 512;
    int E = in_sizes[1] / 2;
    const int* srcI = ei;
    const int* dstI = ei + E;

    char* wsb = (char*)d_ws;
    size_t off = 0;
    auto alloc = [&](size_t bytes) {
        void* p = wsb + off;
        off = (off + bytes + 255) & ~(size_t)255;
        return p;
    };
    int*   cnt      = (int*)alloc((size_t)N * 4);
    int*   cursor   = (int*)alloc((size_t)N * 4);
    float* dinv     = (float*)alloc((size_t)N * 4);
    int*   rp       = (int*)alloc((size_t)(N + 1) * 4);
    int*   partials = (int*)alloc(1024 * 4);
    float* W2T      = (float*)alloc(128 * 128 * 4);
    int*   col      = (int*)alloc((size_t)E * 4);
    float* h1       = (float*)alloc((size_t)N * 128 * 4);
    float* a1       = (float*)alloc((size_t)N * 128 * 4);
    float* g2       = h1;  // h1 dead after agg1; reuse

    hipMemsetAsync(cnt, 0, (size_t)N * 4, stream);
    hipMemsetAsync(cursor, 0, (size_t)N * 4, stream);

    k_degree<<<(E + 255) / 256, 256, 0, stream>>>(dstI, E, cnt);
    k_dinv<<<(N + 255) / 256, 256, 0, stream>>>(cnt, dinv, N);
    int nb = (N + 511) / 512;
    k_scan1<<<nb, 512, 0, stream>>>(cnt, rp, partials, N);
    k_scan2<<<1, 64, 0, stream>>>(partials, nb);
    k_scan3<<<nb, 512, 0, stream>>>(rp, partials, N, E);
    k_fill<<<(E + 255) / 256, 256, 0, stream>>>(srcI, dstI, E, rp, cursor, col);
    k_transpose<<<(128 * 100 + 255) / 256, 256, 0, stream>>>(W2, W2T);

    k_gemm1<<<(N + 63) / 64, 256, 0, stream>>>(x, W1, h1, N);
    k_agg<true><<<(N + 3) / 4, 256, 0, stream>>>(h1, dinv, rp, col, b1, a1, N);
    k_agg<false><<<(N + 3) / 4, 256, 0, stream>>>(a1, dinv, rp, col, nullptr, g2, N);
    k_out<<<(N + 3) / 4, 256, 0, stream>>>(g2, W2T, b2, out, N);
}

// Round 3
// 714.761 us; speedup vs baseline: 1.8629x; 1.8629x over previous
//
#include <hip/hip_runtime.h>
#include <math.h>

typedef __attribute__((ext_vector_type(8))) short short8;
typedef __attribute__((ext_vector_type(4))) float f32x4;
typedef unsigned int uint;

__device__ inline uint f2bf(float f) {            // RNE float->bf16 (returns low 16 bits)
    uint u = __float_as_uint(f);
    return (u + 0x7fffu + ((u >> 16) & 1u)) >> 16;
}
__device__ inline uint pack2(float lo, float hi) { return f2bf(lo) | (f2bf(hi) << 16); }
__device__ inline float bflo(uint u) { return __uint_as_float(u << 16); }
__device__ inline float bfhi(uint u) { return __uint_as_float(u & 0xffff0000u); }

// ---------------- degree / norm ----------------
__global__ void k_degree(const int* __restrict__ dst, int E, int* __restrict__ cnt) {
    int i = blockIdx.x * 256 + threadIdx.x;
    if (i < E) atomicAdd(&cnt[dst[i]], 1);
}

__global__ void k_dinv(const int* __restrict__ cnt, float* __restrict__ dinv, int N) {
    int i = blockIdx.x * 256 + threadIdx.x;
    if (i < N) dinv[i] = rsqrtf((float)(cnt[i] + 1));  // +1 self loop
}

// ---------------- scan for CSR row_ptr ----------------
__global__ __launch_bounds__(512) void k_scan1(const int* __restrict__ cnt, int* __restrict__ rp,
                                               int* __restrict__ partials, int N) {
    __shared__ int s[512];
    int i = blockIdx.x * 512 + threadIdx.x;
    int v = (i < N) ? cnt[i] : 0;
    s[threadIdx.x] = v;
    __syncthreads();
    for (int d = 1; d < 512; d <<= 1) {
        int t = (threadIdx.x >= d) ? s[threadIdx.x - d] : 0;
        __syncthreads();
        s[threadIdx.x] += t;
        __syncthreads();
    }
    if (i < N) rp[i] = s[threadIdx.x] - v;
    if (threadIdx.x == 511) partials[blockIdx.x] = s[511];
}

__global__ void k_scan2(int* __restrict__ partials, int nb) {
    if (threadIdx.x == 0 && blockIdx.x == 0) {
        int acc = 0;
        for (int i = 0; i < nb; i++) { int v = partials[i]; partials[i] = acc; acc += v; }
    }
}

__global__ __launch_bounds__(512) void k_scan3(int* __restrict__ rp, const int* __restrict__ partials,
                                               int N, int E) {
    int i = blockIdx.x * 512 + threadIdx.x;
    if (i < N) rp[i] += partials[blockIdx.x];
    if (i == 0) rp[N] = E;
}

__global__ void k_fill(const int* __restrict__ src, const int* __restrict__ dst, int E,
                       const int* __restrict__ rp, int* __restrict__ cursor, int* __restrict__ col) {
    int i = blockIdx.x * 256 + threadIdx.x;
    if (i < E) {
        int d = dst[i];
        int pos = rp[d] + atomicAdd(&cursor[d], 1);
        col[pos] = src[i];
    }
}

// ---------------- GEMM1: h = x @ W1 (fp32 compute, bf16 store) ----------------
__global__ __launch_bounds__(256) void k_gemm1(const float* __restrict__ x, const float* __restrict__ W,
                                               uint* __restrict__ h, int N) {
    __shared__ float xs[64][36];
    __shared__ float ws[32][128];
    int tid = threadIdx.x;
    int n0 = blockIdx.x * 64;
    int tx = tid & 15, ty = tid >> 4;
    float acc[4][8];
#pragma unroll
    for (int i = 0; i < 4; i++)
#pragma unroll
        for (int j = 0; j < 8; j++) acc[i][j] = 0.f;

    int lr = tid >> 3;
    int lf = tid & 7;
    int wq = tid & 31;
    int wr = tid >> 5;

    for (int k0 = 0; k0 < 512; k0 += 32) {
#pragma unroll
        for (int t = 0; t < 2; t++) {
            int r = lr + 32 * t;
            int gr = n0 + r;
            float4 v = make_float4(0.f, 0.f, 0.f, 0.f);
            if (gr < N) v = *(const float4*)&x[(size_t)gr * 512 + k0 + lf * 4];
            *(float4*)&xs[r][lf * 4] = v;
        }
#pragma unroll
        for (int t = 0; t < 4; t++) {
            int r = wr + 8 * t;
            *(float4*)&ws[r][wq * 4] = *(const float4*)&W[(size_t)(k0 + r) * 128 + wq * 4];
        }
        __syncthreads();
#pragma unroll
        for (int kk = 0; kk < 32; kk += 4) {
            float4 av[4];
#pragma unroll
            for (int i = 0; i < 4; i++) av[i] = *(float4*)&xs[ty * 4 + i][kk];
#pragma unroll
            for (int u = 0; u < 4; u++) {
                float4 b0 = *(float4*)&ws[kk + u][tx * 8];
                float4 b1 = *(float4*)&ws[kk + u][tx * 8 + 4];
#pragma unroll
                for (int i = 0; i < 4; i++) {
                    float a = (&av[i].x)[u];
                    acc[i][0] = fmaf(a, b0.x, acc[i][0]);
                    acc[i][1] = fmaf(a, b0.y, acc[i][1]);
                    acc[i][2] = fmaf(a, b0.z, acc[i][2]);
                    acc[i][3] = fmaf(a, b0.w, acc[i][3]);
                    acc[i][4] = fmaf(a, b1.x, acc[i][4]);
                    acc[i][5] = fmaf(a, b1.y, acc[i][5]);
                    acc[i][6] = fmaf(a, b1.z, acc[i][6]);
                    acc[i][7] = fmaf(a, b1.w, acc[i][7]);
                }
            }
        }
        __syncthreads();
    }
#pragma unroll
    for (int i = 0; i < 4; i++) {
        int gr = n0 + ty * 4 + i;
        if (gr < N) {
            uint4 o;
            o.x = pack2(acc[i][0], acc[i][1]);
            o.y = pack2(acc[i][2], acc[i][3]);
            o.z = pack2(acc[i][4], acc[i][5]);
            o.w = pack2(acc[i][6], acc[i][7]);
            ((uint4*)&h[(size_t)gr * 64])[tx] = o;
        }
    }
}

// ---------------- aggregation over bf16 feature table (fp32 accum, bf16 out) ----------------
// h rows: 128 bf16 = 64 uints; lane owns feats {2*lane, 2*lane+1}.
template <bool RELU_BIAS>
__global__ __launch_bounds__(256) void k_agg(const uint* __restrict__ h, const float* __restrict__ dinv,
                                             const int* __restrict__ rp, const int* __restrict__ col,
                                             const float* __restrict__ bias, uint* __restrict__ outb, int N) {
    int wave = threadIdx.x >> 6, lane = threadIdx.x & 63;
    int v = blockIdx.x * 4 + wave;
    if (v >= N) return;
    float dv = dinv[v];
    float wself = dv * dv;
    uint us = h[(size_t)v * 64 + lane];
    float acc0 = bflo(us) * wself;
    float acc1 = bfhi(us) * wself;
    int e0 = rp[v], e1 = rp[v + 1];
    for (int i = e0; i < e1; i++) {
        int c = col[i];
        float w = dinv[c] * dv;
        uint u = h[(size_t)c * 64 + lane];
        acc0 = fmaf(bflo(u), w, acc0);
        acc1 = fmaf(bfhi(u), w, acc1);
    }
    if (RELU_BIAS) {
        float2 b = *(const float2*)&bias[2 * lane];
        acc0 = fmaxf(acc0 + b.x, 0.f);
        acc1 = fmaxf(acc1 + b.y, 0.f);
    }
    outb[(size_t)v * 64 + lane] = pack2(acc0, acc1);
}

// ---------------- W2 -> bf16 B-fragment layout [q(4)][t(7)][lane(64)][j(8)], b2 padded ----------------
__global__ void k_w2prep(const float* __restrict__ W2, const float* __restrict__ b2,
                         ushort* __restrict__ frag, float* __restrict__ b2pad) {
    int tid = blockIdx.x * 256 + threadIdx.x;
    if (tid < 1792) {
        int q = tid / 448;
        int t = (tid >> 6) % 7;
        int l = tid & 63;
        int kbase = q * 32 + (l >> 4) * 8;
        int c = t * 16 + (l & 15);
#pragma unroll
        for (int j = 0; j < 8; j++) {
            float v = (c < 100) ? W2[(kbase + j) * 100 + c] : 0.f;
            frag[(size_t)tid * 8 + j] = (ushort)f2bf(v);
        }
    } else if (tid < 1792 + 112) {
        int c = tid - 1792;
        b2pad[c] = (c < 100) ? b2[c] : -1e30f;
    }
}

// ---------------- fused MFMA GEMM2 + log_softmax ----------------
// block: 4 waves x 32 nodes = 128 nodes. A = g2 (bf16, M=16xK=32 frags from global),
// B = W2 frags staged in LDS. C layout: col=lane&15, row=(lane>>4)*4+reg.
__global__ __launch_bounds__(256) void k_out_mfma(const uint* __restrict__ g2u,
                                                  const uint4* __restrict__ w2fragG,
                                                  const float* __restrict__ b2pad,
                                                  float* __restrict__ out, int N) {
    __shared__ uint4 w2s[1792];
    __shared__ float b2s[112];
    int tid = threadIdx.x;
    for (int i = tid; i < 1792; i += 256) w2s[i] = w2fragG[i];
    if (tid < 112) b2s[tid] = b2pad[tid];
    __syncthreads();

    int w = tid >> 6, l = tid & 63;
    int v0 = blockIdx.x * 128 + w * 32;
    int cl = l & 15, gq = l >> 4;

    f32x4 acc[2][7];
#pragma unroll
    for (int m = 0; m < 2; m++)
#pragma unroll
        for (int t = 0; t < 7; t++) acc[m][t] = (f32x4){0.f, 0.f, 0.f, 0.f};

    union U { uint4 u4; short8 s8; };

#pragma unroll
    for (int q = 0; q < 4; q++) {
        short8 afr[2];
#pragma unroll
        for (int m = 0; m < 2; m++) {
            int rv = v0 + m * 16 + cl;
            if (rv >= N) rv = N - 1;
            U a;
            a.u4 = *(const uint4*)&g2u[(size_t)rv * 64 + q * 16 + gq * 4];
            afr[m] = a.s8;
        }
#pragma unroll
        for (int t = 0; t < 7; t++) {
            U b;
            b.u4 = w2s[(q * 7 + t) * 64 + l];
            acc[0][t] = __builtin_amdgcn_mfma_f32_16x16x32_bf16(afr[0], b.s8, acc[0][t], 0, 0, 0);
            acc[1][t] = __builtin_amdgcn_mfma_f32_16x16x32_bf16(afr[1], b.s8, acc[1][t], 0, 0, 0);
        }
    }

    float bsv[7];
#pragma unroll
    for (int t = 0; t < 7; t++) bsv[t] = b2s[t * 16 + cl];

#pragma unroll
    for (int m = 0; m < 2; m++) {
#pragma unroll
        for (int r = 0; r < 4; r++) {
            int row = v0 + m * 16 + gq * 4 + r;
            float lg[7];
#pragma unroll
            for (int t = 0; t < 7; t++) lg[t] = acc[m][t][r] + bsv[t];
            float mx = lg[0];
#pragma unroll
            for (int t = 1; t < 7; t++) mx = fmaxf(mx, lg[t]);
            mx = fmaxf(mx, __shfl_xor(mx, 1, 64));
            mx = fmaxf(mx, __shfl_xor(mx, 2, 64));
            mx = fmaxf(mx, __shfl_xor(mx, 4, 64));
            mx = fmaxf(mx, __shfl_xor(mx, 8, 64));
            float s = 0.f;
#pragma unroll
            for (int t = 0; t < 7; t++) s += __expf(lg[t] - mx);
            s += __shfl_xor(s, 1, 64);
            s += __shfl_xor(s, 2, 64);
            s += __shfl_xor(s, 4, 64);
            s += __shfl_xor(s, 8, 64);
            float lse = mx + __logf(s);
            if (row < N) {
#pragma unroll
                for (int t = 0; t < 7; t++) {
                    int c = t * 16 + cl;
                    if (c < 100) out[(size_t)row * 100 + c] = lg[t] - lse;
                }
            }
        }
    }
}

extern "C" void kernel_launch(void* const* d_in, const int* in_sizes, int n_in,
                              void* d_out, int out_size, void* d_ws, size_t ws_size,
                              hipStream_t stream) {
    const float* x  = (const float*)d_in[0];
    const int*   ei = (const int*)d_in[1];   // int32 (JAX x64 disabled)
    const float* W1 = (const float*)d_in[2];
    const float* b1 = (const float*)d_in[3];
    const float* W2 = (const float*)d_in[4];
    const float* b2 = (const float*)d_in[5];
    float* out = (float*)d_out;

    int N = in_sizes[0] / 512;
    int E = in_sizes[1] / 2;
    const int* srcI = ei;
    const int* dstI = ei + E;

    char* wsb = (char*)d_ws;
    size_t off = 0;
    auto alloc = [&](size_t bytes) {
        void* p = wsb + off;
        off = (off + bytes + 255) & ~(size_t)255;
        return p;
    };
    int*    cnt      = (int*)alloc((size_t)N * 4);
    int*    cursor   = (int*)alloc((size_t)N * 4);
    float*  dinv     = (float*)alloc((size_t)N * 4);
    int*    rp       = (int*)alloc((size_t)(N + 1) * 4);
    int*    partials = (int*)alloc(1024 * 4);
    ushort* w2frag   = (ushort*)alloc(1792 * 8 * 2);
    float*  b2pad    = (float*)alloc(112 * 4);
    int*    col      = (int*)alloc((size_t)E * 4);
    uint*   h1       = (uint*)alloc((size_t)N * 64 * 4);   // bf16 x128 per row
    uint*   a1       = (uint*)alloc((size_t)N * 64 * 4);
    uint*   g2       = h1;  // h1 dead after agg1; reuse

    hipMemsetAsync(cnt, 0, (size_t)N * 4, stream);
    hipMemsetAsync(cursor, 0, (size_t)N * 4, stream);

    k_degree<<<(E + 255) / 256, 256, 0, stream>>>(dstI, E, cnt);
    k_dinv<<<(N + 255) / 256, 256, 0, stream>>>(cnt, dinv, N);
    int nb = (N + 511) / 512;
    k_scan1<<<nb, 512, 0, stream>>>(cnt, rp, partials, N);
    k_scan2<<<1, 64, 0, stream>>>(partials, nb);
    k_scan3<<<nb, 512, 0, stream>>>(rp, partials, N, E);
    k_fill<<<(E + 255) / 256, 256, 0, stream>>>(srcI, dstI, E, rp, cursor, col);
    k_w2prep<<<8, 256, 0, stream>>>(W2, b2, w2frag, b2pad);

    k_gemm1<<<(N + 63) / 64, 256, 0, stream>>>(x, W1, h1, N);
    k_agg<true><<<(N + 3) / 4, 256, 0, stream>>>(h1, dinv, rp, col, b1, a1, N);
    k_agg<false><<<(N + 3) / 4, 256, 0, stream>>>(a1, dinv, rp, col, nullptr, g2, N);
    k_out_mfma<<<(N + 127) / 128, 256, 0, stream>>>(g2, (const uint4*)w2frag, b2pad, out, N);
}

// Round 4
// 611.374 us; speedup vs baseline: 2.1780x; 1.1691x over previous
//
#include <hip/hip_runtime.h>
#include <math.h>

typedef __attribute__((ext_vector_type(8))) short short8;
typedef __attribute__((ext_vector_type(4))) float f32x4;
typedef unsigned int uint;

__device__ inline uint f2bf(float f) {            // RNE float->bf16 (returns low 16 bits)
    uint u = __float_as_uint(f);
    return (u + 0x7fffu + ((u >> 16) & 1u)) >> 16;
}
__device__ inline uint pack2(float lo, float hi) { return f2bf(lo) | (f2bf(hi) << 16); }
__device__ inline float bflo(uint u) { return __uint_as_float(u << 16); }
__device__ inline float bfhi(uint u) { return __uint_as_float(u & 0xffff0000u); }
__device__ inline uint cvtpk(float lo, float hi) {
    uint r;
    asm("v_cvt_pk_bf16_f32 %0, %1, %2" : "=v"(r) : "v"(lo), "v"(hi));
    return r;
}

// ---------------- degree / norm ----------------
__global__ void k_degree(const int* __restrict__ dst, int E, int* __restrict__ cnt) {
    int i = blockIdx.x * 256 + threadIdx.x;
    if (i < E) atomicAdd(&cnt[dst[i]], 1);
}

__global__ void k_dinv(const int* __restrict__ cnt, float* __restrict__ dinv, int N) {
    int i = blockIdx.x * 256 + threadIdx.x;
    if (i < N) dinv[i] = rsqrtf((float)(cnt[i] + 1));  // +1 self loop
}

// ---------------- scan for CSR row_ptr ----------------
__global__ __launch_bounds__(512) void k_scan1(const int* __restrict__ cnt, int* __restrict__ rp,
                                               int* __restrict__ partials, int N) {
    __shared__ int s[512];
    int i = blockIdx.x * 512 + threadIdx.x;
    int v = (i < N) ? cnt[i] : 0;
    s[threadIdx.x] = v;
    __syncthreads();
    for (int d = 1; d < 512; d <<= 1) {
        int t = (threadIdx.x >= d) ? s[threadIdx.x - d] : 0;
        __syncthreads();
        s[threadIdx.x] += t;
        __syncthreads();
    }
    if (i < N) rp[i] = s[threadIdx.x] - v;
    if (threadIdx.x == 511) partials[blockIdx.x] = s[511];
}

__global__ void k_scan2(int* __restrict__ partials, int nb) {
    if (threadIdx.x == 0 && blockIdx.x == 0) {
        int acc = 0;
        for (int i = 0; i < nb; i++) { int v = partials[i]; partials[i] = acc; acc += v; }
    }
}

__global__ __launch_bounds__(512) void k_scan3(int* __restrict__ rp, const int* __restrict__ partials,
                                               int N, int E) {
    int i = blockIdx.x * 512 + threadIdx.x;
    if (i < N) rp[i] += partials[blockIdx.x];
    if (i == 0) rp[N] = E;
}

__global__ void k_fill(const int* __restrict__ src, const int* __restrict__ dst, int E,
                       const int* __restrict__ rp, int* __restrict__ cursor, int* __restrict__ col) {
    int i = blockIdx.x * 256 + threadIdx.x;
    if (i < E) {
        int d = dst[i];
        int pos = rp[d] + atomicAdd(&cursor[d], 1);
        col[pos] = src[i];
    }
}

// ---------------- W1 -> bf16 B-fragment layout [ks(16)][t(8)][lane(64)][j(8)] ----------------
__global__ void k_w1prep(const float* __restrict__ W1, ushort* __restrict__ frag) {
    int tid = blockIdx.x * 256 + threadIdx.x;
    if (tid < 8192) {
        int ks = tid >> 9;          // k-step (32 K each)
        int t = (tid >> 6) & 7;     // col frag
        int l = tid & 63;
        int kbase = ks * 32 + (l >> 4) * 8;
        int c = t * 16 + (l & 15);
#pragma unroll
        for (int j = 0; j < 8; j++)
            frag[(size_t)tid * 8 + j] = (ushort)f2bf(W1[(size_t)(kbase + j) * 128 + c]);
    }
}

// ---------------- GEMM1 (MFMA): h1 = bf16(x @ W1), packed bf16 rows ----------------
// 256 thr = 4 waves; each wave 16 rows x 128 cols; K=512 in 16 steps of 32.
__global__ __launch_bounds__(256) void k_gemm1(const float* __restrict__ x,
                                               const uint4* __restrict__ w1frag,
                                               uint* __restrict__ h1, int N) {
    __shared__ float hs[4][16][128];   // 32 KB: C transpose staging
    int tid = threadIdx.x, wv = tid >> 6, l = tid & 63;
    int cl = l & 15, kg = l >> 4;
    int n0 = blockIdx.x * 64 + wv * 16;
    int row = n0 + cl;
    int rv = row < N ? row : N - 1;
    const float* xrow = x + (size_t)rv * 512 + kg * 8;

    f32x4 acc[8];
#pragma unroll
    for (int t = 0; t < 8; t++) acc[t] = (f32x4){0.f, 0.f, 0.f, 0.f};

    union U { uint4 u4; short8 s8; };

#pragma unroll 4
    for (int ks = 0; ks < 16; ks++) {
        float4 a0 = *(const float4*)(xrow + ks * 32);
        float4 a1 = *(const float4*)(xrow + ks * 32 + 4);
        U A;
        A.u4.x = cvtpk(a0.x, a0.y);
        A.u4.y = cvtpk(a0.z, a0.w);
        A.u4.z = cvtpk(a1.x, a1.y);
        A.u4.w = cvtpk(a1.z, a1.w);
#pragma unroll
        for (int t = 0; t < 8; t++) {
            U B;
            B.u4 = w1frag[(ks * 8 + t) * 64 + l];
            acc[t] = __builtin_amdgcn_mfma_f32_16x16x32_bf16(A.s8, B.s8, acc[t], 0, 0, 0);
        }
    }

    // C frag (col = l&15, rows kg*4+r) -> LDS -> packed bf16 rows
#pragma unroll
    for (int t = 0; t < 8; t++)
#pragma unroll
        for (int r = 0; r < 4; r++)
            hs[wv][kg * 4 + r][t * 16 + cl] = acc[t][r];
    __syncthreads();
#pragma unroll
    for (int it = 0; it < 16; it++) {
        int gr = n0 + it;
        if (gr < N) {
            float2 p = *(float2*)&hs[wv][it][l * 2];
            h1[(size_t)gr * 64 + l] = cvtpk(p.x, p.y);
        }
    }
}

// ---------------- aggregation over bf16 feature table (fp32 accum, bf16 out) ----------------
template <bool RELU_BIAS>
__global__ __launch_bounds__(256) void k_agg(const uint* __restrict__ h, const float* __restrict__ dinv,
                                             const int* __restrict__ rp, const int* __restrict__ col,
                                             const float* __restrict__ bias, uint* __restrict__ outb, int N) {
    int wave = threadIdx.x >> 6, lane = threadIdx.x & 63;
    int v = blockIdx.x * 4 + wave;
    if (v >= N) return;
    float dv = dinv[v];
    float wself = dv * dv;
    uint us = h[(size_t)v * 64 + lane];
    float acc0 = bflo(us) * wself;
    float acc1 = bfhi(us) * wself;
    int e0 = rp[v], e1 = rp[v + 1];
    for (int i = e0; i < e1; i++) {
        int c = col[i];
        float w = dinv[c] * dv;
        uint u = h[(size_t)c * 64 + lane];
        acc0 = fmaf(bflo(u), w, acc0);
        acc1 = fmaf(bfhi(u), w, acc1);
    }
    if (RELU_BIAS) {
        float2 b = *(const float2*)&bias[2 * lane];
        acc0 = fmaxf(acc0 + b.x, 0.f);
        acc1 = fmaxf(acc1 + b.y, 0.f);
    }
    outb[(size_t)v * 64 + lane] = pack2(acc0, acc1);
}

// ---------------- W2 -> bf16 B-fragment layout [q(4)][t(7)][lane(64)][j(8)], b2 padded ----------------
__global__ void k_w2prep(const float* __restrict__ W2, const float* __restrict__ b2,
                         ushort* __restrict__ frag, float* __restrict__ b2pad) {
    int tid = blockIdx.x * 256 + threadIdx.x;
    if (tid < 1792) {
        int q = tid / 448;
        int t = (tid >> 6) % 7;
        int l = tid & 63;
        int kbase = q * 32 + (l >> 4) * 8;
        int c = t * 16 + (l & 15);
#pragma unroll
        for (int j = 0; j < 8; j++) {
            float v = (c < 100) ? W2[(kbase + j) * 100 + c] : 0.f;
            frag[(size_t)tid * 8 + j] = (ushort)f2bf(v);
        }
    } else if (tid < 1792 + 112) {
        int c = tid - 1792;
        b2pad[c] = (c < 100) ? b2[c] : -1e30f;
    }
}

// ---------------- fused MFMA GEMM2 + log_softmax ----------------
__global__ __launch_bounds__(256) void k_out_mfma(const uint* __restrict__ g2u,
                                                  const uint4* __restrict__ w2fragG,
                                                  const float* __restrict__ b2pad,
                                                  float* __restrict__ out, int N) {
    __shared__ uint4 w2s[1792];
    __shared__ float b2s[112];
    int tid = threadIdx.x;
    for (int i = tid; i < 1792; i += 256) w2s[i] = w2fragG[i];
    if (tid < 112) b2s[tid] = b2pad[tid];
    __syncthreads();

    int w = tid >> 6, l = tid & 63;
    int v0 = blockIdx.x * 128 + w * 32;
    int cl = l & 15, gq = l >> 4;

    f32x4 acc[2][7];
#pragma unroll
    for (int m = 0; m < 2; m++)
#pragma unroll
        for (int t = 0; t < 7; t++) acc[m][t] = (f32x4){0.f, 0.f, 0.f, 0.f};

    union U { uint4 u4; short8 s8; };

#pragma unroll
    for (int q = 0; q < 4; q++) {
        short8 afr[2];
#pragma unroll
        for (int m = 0; m < 2; m++) {
            int rv = v0 + m * 16 + cl;
            if (rv >= N) rv = N - 1;
            U a;
            a.u4 = *(const uint4*)&g2u[(size_t)rv * 64 + q * 16 + gq * 4];
            afr[m] = a.s8;
        }
#pragma unroll
        for (int t = 0; t < 7; t++) {
            U b;
            b.u4 = w2s[(q * 7 + t) * 64 + l];
            acc[0][t] = __builtin_amdgcn_mfma_f32_16x16x32_bf16(afr[0], b.s8, acc[0][t], 0, 0, 0);
            acc[1][t] = __builtin_amdgcn_mfma_f32_16x16x32_bf16(afr[1], b.s8, acc[1][t], 0, 0, 0);
        }
    }

    float bsv[7];
#pragma unroll
    for (int t = 0; t < 7; t++) bsv[t] = b2s[t * 16 + cl];

#pragma unroll
    for (int m = 0; m < 2; m++) {
#pragma unroll
        for (int r = 0; r < 4; r++) {
            int row = v0 + m * 16 + gq * 4 + r;
            float lg[7];
#pragma unroll
            for (int t = 0; t < 7; t++) lg[t] = acc[m][t][r] + bsv[t];
            float mx = lg[0];
#pragma unroll
            for (int t = 1; t < 7; t++) mx = fmaxf(mx, lg[t]);
            mx = fmaxf(mx, __shfl_xor(mx, 1, 64));
            mx = fmaxf(mx, __shfl_xor(mx, 2, 64));
            mx = fmaxf(mx, __shfl_xor(mx, 4, 64));
            mx = fmaxf(mx, __shfl_xor(mx, 8, 64));
            float s = 0.f;
#pragma unroll
            for (int t = 0; t < 7; t++) s += __expf(lg[t] - mx);
            s += __shfl_xor(s, 1, 64);
            s += __shfl_xor(s, 2, 64);
            s += __shfl_xor(s, 4, 64);
            s += __shfl_xor(s, 8, 64);
            float lse = mx + __logf(s);
            if (row < N) {
#pragma unroll
                for (int t = 0; t < 7; t++) {
                    int c = t * 16 + cl;
                    if (c < 100) out[(size_t)row * 100 + c] = lg[t] - lse;
                }
            }
        }
    }
}

extern "C" void kernel_launch(void* const* d_in, const int* in_sizes, int n_in,
                              void* d_out, int out_size, void* d_ws, size_t ws_size,
                              hipStream_t stream) {
    const float* x  = (const float*)d_in[0];
    const int*   ei = (const int*)d_in[1];   // int32 (JAX x64 disabled)
    const float* W1 = (const float*)d_in[2];
    const float* b1 = (const float*)d_in[3];
    const float* W2 = (const float*)d_in[4];
    const float* b2 = (const float*)d_in[5];
    float* out = (float*)d_out;

    int N = in_sizes[0] / 512;
    int E = in_sizes[1] / 2;
    const int* srcI = ei;
    const int* dstI = ei + E;

    char* wsb = (char*)d_ws;
    size_t off = 0;
    auto alloc = [&](size_t bytes) {
        void* p = wsb + off;
        off = (off + bytes + 255) & ~(size_t)255;
        return p;
    };
    int*    cnt      = (int*)alloc((size_t)N * 4);
    int*    cursor   = (int*)alloc((size_t)N * 4);
    float*  dinv     = (float*)alloc((size_t)N * 4);
    int*    rp       = (int*)alloc((size_t)(N + 1) * 4);
    int*    partials = (int*)alloc(1024 * 4);
    ushort* w1frag   = (ushort*)alloc(8192 * 8 * 2);   // 131 KB
    ushort* w2frag   = (ushort*)alloc(1792 * 8 * 2);
    float*  b2pad    = (float*)alloc(112 * 4);
    int*    col      = (int*)alloc((size_t)E * 4);
    uint*   h1       = (uint*)alloc((size_t)N * 64 * 4);   // bf16 x128 per row
    uint*   a1       = (uint*)alloc((size_t)N * 64 * 4);
    uint*   g2       = h1;  // h1 dead after agg1; reuse

    hipMemsetAsync(cnt, 0, (size_t)N * 4, stream);
    hipMemsetAsync(cursor, 0, (size_t)N * 4, stream);

    k_degree<<<(E + 255) / 256, 256, 0, stream>>>(dstI, E, cnt);
    k_dinv<<<(N + 255) / 256, 256, 0, stream>>>(cnt, dinv, N);
    int nb = (N + 511) / 512;
    k_scan1<<<nb, 512, 0, stream>>>(cnt, rp, partials, N);
    k_scan2<<<1, 64, 0, stream>>>(partials, nb);
    k_scan3<<<nb, 512, 0, stream>>>(rp, partials, N, E);
    k_fill<<<(E + 255) / 256, 256, 0, stream>>>(srcI, dstI, E, rp, cursor, col);
    k_w1prep<<<32, 256, 0, stream>>>(W1, w1frag);
    k_w2prep<<<8, 256, 0, stream>>>(W2, b2, w2frag, b2pad);

    k_gemm1<<<(N + 63) / 64, 256, 0, stream>>>(x, (const uint4*)w1frag, h1, N);
    k_agg<true><<<(N + 3) / 4, 256, 0, stream>>>(h1, dinv, rp, col, b1, a1, N);
    k_agg<false><<<(N + 3) / 4, 256, 0, stream>>>(a1, dinv, rp, col, nullptr, g2, N);
    k_out_mfma<<<(N + 127) / 128, 256, 0, stream>>>(g2, (const uint4*)w2frag, b2pad, out, N);
}

// Round 5
// 470.761 us; speedup vs baseline: 2.8285x; 1.2987x over previous
//
#include <hip/hip_runtime.h>
#include <math.h>

typedef __attribute__((ext_vector_type(8))) short short8;
typedef __attribute__((ext_vector_type(4))) float f32x4;
typedef unsigned int uint;

__device__ inline uint f2bf(float f) {            // RNE float->bf16 (low 16 bits)
    uint u = __float_as_uint(f);
    return (u + 0x7fffu + ((u >> 16) & 1u)) >> 16;
}
__device__ inline uint pack2(float lo, float hi) { return f2bf(lo) | (f2bf(hi) << 16); }
__device__ inline float bflo(uint u) { return __uint_as_float(u << 16); }
__device__ inline float bfhi(uint u) { return __uint_as_float(u & 0xffff0000u); }
__device__ inline uint cvtpk(float lo, float hi) {
    uint r;
    asm("v_cvt_pk_bf16_f32 %0, %1, %2" : "=v"(r) : "v"(lo), "v"(hi));
    return r;
}

// ---------------- degree / norm ----------------
__global__ void k_degree(const int* __restrict__ dst, int E, int* __restrict__ cnt) {
    int i = blockIdx.x * 256 + threadIdx.x;
    if (i < E) atomicAdd(&cnt[dst[i]], 1);
}

__global__ void k_dinv(const int* __restrict__ cnt, float* __restrict__ dinv, int N) {
    int i = blockIdx.x * 256 + threadIdx.x;
    if (i < N) dinv[i] = rsqrtf((float)(cnt[i] + 1));  // +1 self loop
}

// ---------------- scan for CSR row_ptr ----------------
__global__ __launch_bounds__(512) void k_scan1(const int* __restrict__ cnt, int* __restrict__ rp,
                                               int* __restrict__ partials, int N) {
    __shared__ int s[512];
    int i = blockIdx.x * 512 + threadIdx.x;
    int v = (i < N) ? cnt[i] : 0;
    s[threadIdx.x] = v;
    __syncthreads();
    for (int d = 1; d < 512; d <<= 1) {
        int t = (threadIdx.x >= d) ? s[threadIdx.x - d] : 0;
        __syncthreads();
        s[threadIdx.x] += t;
        __syncthreads();
    }
    if (i < N) rp[i] = s[threadIdx.x] - v;
    if (threadIdx.x == 511) partials[blockIdx.x] = s[511];
}

__global__ void k_scan2(int* __restrict__ partials, int nb) {
    if (threadIdx.x == 0 && blockIdx.x == 0) {
        int acc = 0;
        for (int i = 0; i < nb; i++) { int v = partials[i]; partials[i] = acc; acc += v; }
    }
}

__global__ __launch_bounds__(512) void k_scan3(int* __restrict__ rp, const int* __restrict__ partials,
                                               int N, int E) {
    int i = blockIdx.x * 512 + threadIdx.x;
    if (i < N) rp[i] += partials[blockIdx.x];
    if (i == 0) rp[N] = E;
}

// edge record: (src as float-bits, dinv[src]) -> removes chained dinv lookup in agg
__global__ void k_fill(const int* __restrict__ src, const int* __restrict__ dst, int E,
                       const int* __restrict__ rp, int* __restrict__ cursor,
                       const float* __restrict__ dinv, float2* __restrict__ colw) {
    int i = blockIdx.x * 256 + threadIdx.x;
    if (i < E) {
        int d = dst[i];
        int s = src[i];
        int pos = rp[d] + atomicAdd(&cursor[d], 1);
        colw[pos] = make_float2(__int_as_float(s), dinv[s]);
    }
}

// ---------------- W1 -> hi/lo bf16 B-fragments [ks(16)][t(8)][lane(64)][j(8)] ----------------
__global__ void k_w1prep(const float* __restrict__ W1, ushort* __restrict__ fragHi,
                         ushort* __restrict__ fragLo) {
    int tid = blockIdx.x * 256 + threadIdx.x;
    if (tid < 8192) {
        int ks = tid >> 9;
        int t = (tid >> 6) & 7;
        int l = tid & 63;
        int kbase = ks * 32 + (l >> 4) * 8;
        int c = t * 16 + (l & 15);
#pragma unroll
        for (int j = 0; j < 8; j++) {
            float v = W1[(size_t)(kbase + j) * 128 + c];
            uint hb = f2bf(v);
            float vh = __uint_as_float(hb << 16);
            fragHi[(size_t)tid * 8 + j] = (ushort)hb;
            fragLo[(size_t)tid * 8 + j] = (ushort)f2bf(v - vh);
        }
    }
}

// ---------------- GEMM1 (MFMA, split precision): h1 = bf16(x @ W1) ----------------
// 4 waves x 32 rows = 128 rows/block. Per wave: 2 A-frags share each B-load.
__global__ __launch_bounds__(256) void k_gemm1(const float* __restrict__ x,
                                               const uint4* __restrict__ w1hi,
                                               const uint4* __restrict__ w1lo,
                                               uint* __restrict__ h1, int N) {
    __shared__ uint hsp[4][32][66];   // packed bf16 pairs, pad 66 -> conflict-free
    int tid = threadIdx.x, wv = tid >> 6, l = tid & 63;
    int cl = l & 15, kg = l >> 4;
    int n0 = blockIdx.x * 128 + wv * 32;
    int r0 = n0 + cl;       if (r0 >= N) r0 = N - 1;
    int r1 = n0 + 16 + cl;  if (r1 >= N) r1 = N - 1;
    const float* xr0 = x + (size_t)r0 * 512 + kg * 8;
    const float* xr1 = x + (size_t)r1 * 512 + kg * 8;

    f32x4 acc[2][8];
#pragma unroll
    for (int m = 0; m < 2; m++)
#pragma unroll
        for (int t = 0; t < 8; t++) acc[m][t] = (f32x4){0.f, 0.f, 0.f, 0.f};

    union U { uint4 u4; short8 s8; };

    for (int ks = 0; ks < 16; ks++) {
        U Ah[2], Al[2];
#pragma unroll
        for (int m = 0; m < 2; m++) {
            const float* xr = m ? xr1 : xr0;
            float4 a0 = *(const float4*)(xr + ks * 32);
            float4 a1 = *(const float4*)(xr + ks * 32 + 4);
            uint p0 = cvtpk(a0.x, a0.y), p1 = cvtpk(a0.z, a0.w);
            uint p2 = cvtpk(a1.x, a1.y), p3 = cvtpk(a1.z, a1.w);
            Ah[m].u4 = make_uint4(p0, p1, p2, p3);
            Al[m].u4 = make_uint4(cvtpk(a0.x - bflo(p0), a0.y - bfhi(p0)),
                                  cvtpk(a0.z - bflo(p1), a0.w - bfhi(p1)),
                                  cvtpk(a1.x - bflo(p2), a1.y - bfhi(p2)),
                                  cvtpk(a1.z - bflo(p3), a1.w - bfhi(p3)));
        }
#pragma unroll
        for (int t = 0; t < 8; t++) {
            U Bh, Bl;
            Bh.u4 = w1hi[(ks * 8 + t) * 64 + l];
            Bl.u4 = w1lo[(ks * 8 + t) * 64 + l];
#pragma unroll
            for (int m = 0; m < 2; m++) {
                acc[m][t] = __builtin_amdgcn_mfma_f32_16x16x32_bf16(Ah[m].s8, Bh.s8, acc[m][t], 0, 0, 0);
                acc[m][t] = __builtin_amdgcn_mfma_f32_16x16x32_bf16(Al[m].s8, Bh.s8, acc[m][t], 0, 0, 0);
                acc[m][t] = __builtin_amdgcn_mfma_f32_16x16x32_bf16(Ah[m].s8, Bl.s8, acc[m][t], 0, 0, 0);
            }
        }
    }

    // C frag (row = m*16+kg*4+r, col = t*16+cl) -> pair via shfl_xor(1) -> packed LDS (wave-private)
#pragma unroll
    for (int m = 0; m < 2; m++)
#pragma unroll
        for (int t = 0; t < 8; t++)
#pragma unroll
            for (int r = 0; r < 4; r++) {
                float mine = acc[m][t][r];
                float other = __shfl_xor(mine, 1, 64);
                if ((cl & 1) == 0)
                    hsp[wv][m * 16 + kg * 4 + r][t * 8 + (cl >> 1)] = cvtpk(mine, other);
            }
    // same-wave LDS write->read: ordered by lgkmcnt, no barrier needed
#pragma unroll
    for (int it = 0; it < 32; it++) {
        int gr = n0 + it;
        if (gr < N) h1[(size_t)gr * 64 + l] = hsp[wv][it][l];
    }
}

// ---------------- aggregation (bf16 table, fp32 accum, unroll-4 for MLP) ----------------
template <bool RELU_BIAS>
__global__ __launch_bounds__(256) void k_agg(const uint* __restrict__ h, const float* __restrict__ dinv,
                                             const int* __restrict__ rp, const float2* __restrict__ colw,
                                             const float* __restrict__ bias, uint* __restrict__ outb, int N) {
    int wave = threadIdx.x >> 6, lane = threadIdx.x & 63;
    int v = blockIdx.x * 4 + wave;
    if (v >= N) return;
    float dv = dinv[v];
    float wself = dv * dv;
    uint us = h[(size_t)v * 64 + lane];
    float acc0 = bflo(us) * wself;
    float acc1 = bfhi(us) * wself;
    int e0 = rp[v], e1 = rp[v + 1];
    int i = e0;
    for (; i + 4 <= e1; i += 4) {
        float2 q0 = colw[i], q1 = colw[i + 1], q2 = colw[i + 2], q3 = colw[i + 3];
        int c0 = __float_as_int(q0.x), c1 = __float_as_int(q1.x);
        int c2 = __float_as_int(q2.x), c3 = __float_as_int(q3.x);
        uint u0 = h[(size_t)c0 * 64 + lane];
        uint u1 = h[(size_t)c1 * 64 + lane];
        uint u2 = h[(size_t)c2 * 64 + lane];
        uint u3 = h[(size_t)c3 * 64 + lane];
        float w0 = q0.y * dv, w1 = q1.y * dv, w2 = q2.y * dv, w3 = q3.y * dv;
        acc0 = fmaf(bflo(u0), w0, acc0); acc1 = fmaf(bfhi(u0), w0, acc1);
        acc0 = fmaf(bflo(u1), w1, acc0); acc1 = fmaf(bfhi(u1), w1, acc1);
        acc0 = fmaf(bflo(u2), w2, acc0); acc1 = fmaf(bfhi(u2), w2, acc1);
        acc0 = fmaf(bflo(u3), w3, acc0); acc1 = fmaf(bfhi(u3), w3, acc1);
    }
    for (; i < e1; i++) {
        float2 q = colw[i];
        int c = __float_as_int(q.x);
        uint u = h[(size_t)c * 64 + lane];
        float w = q.y * dv;
        acc0 = fmaf(bflo(u), w, acc0);
        acc1 = fmaf(bfhi(u), w, acc1);
    }
    if (RELU_BIAS) {
        float2 b = *(const float2*)&bias[2 * lane];
        acc0 = fmaxf(acc0 + b.x, 0.f);
        acc1 = fmaxf(acc1 + b.y, 0.f);
    }
    outb[(size_t)v * 64 + lane] = pack2(acc0, acc1);
}

// ---------------- W2 -> bf16 B-fragment layout [q(4)][t(7)][lane(64)][j(8)], b2 padded ----------------
__global__ void k_w2prep(const float* __restrict__ W2, const float* __restrict__ b2,
                         ushort* __restrict__ frag, float* __restrict__ b2pad) {
    int tid = blockIdx.x * 256 + threadIdx.x;
    if (tid < 1792) {
        int q = tid / 448;
        int t = (tid >> 6) % 7;
        int l = tid & 63;
        int kbase = q * 32 + (l >> 4) * 8;
        int c = t * 16 + (l & 15);
#pragma unroll
        for (int j = 0; j < 8; j++) {
            float v = (c < 100) ? W2[(kbase + j) * 100 + c] : 0.f;
            frag[(size_t)tid * 8 + j] = (ushort)f2bf(v);
        }
    } else if (tid < 1792 + 112) {
        int c = tid - 1792;
        b2pad[c] = (c < 100) ? b2[c] : -1e30f;
    }
}

// ---------------- fused MFMA GEMM2 + log_softmax ----------------
__global__ __launch_bounds__(256) void k_out_mfma(const uint* __restrict__ g2u,
                                                  const uint4* __restrict__ w2fragG,
                                                  const float* __restrict__ b2pad,
                                                  float* __restrict__ out, int N) {
    __shared__ uint4 w2s[1792];
    __shared__ float b2s[112];
    int tid = threadIdx.x;
    for (int i = tid; i < 1792; i += 256) w2s[i] = w2fragG[i];
    if (tid < 112) b2s[tid] = b2pad[tid];
    __syncthreads();

    int w = tid >> 6, l = tid & 63;
    int v0 = blockIdx.x * 128 + w * 32;
    int cl = l & 15, gq = l >> 4;

    f32x4 acc[2][7];
#pragma unroll
    for (int m = 0; m < 2; m++)
#pragma unroll
        for (int t = 0; t < 7; t++) acc[m][t] = (f32x4){0.f, 0.f, 0.f, 0.f};

    union U { uint4 u4; short8 s8; };

#pragma unroll
    for (int q = 0; q < 4; q++) {
        short8 afr[2];
#pragma unroll
        for (int m = 0; m < 2; m++) {
            int rv = v0 + m * 16 + cl;
            if (rv >= N) rv = N - 1;
            U a;
            a.u4 = *(const uint4*)&g2u[(size_t)rv * 64 + q * 16 + gq * 4];
            afr[m] = a.s8;
        }
#pragma unroll
        for (int t = 0; t < 7; t++) {
            U b;
            b.u4 = w2s[(q * 7 + t) * 64 + l];
            acc[0][t] = __builtin_amdgcn_mfma_f32_16x16x32_bf16(afr[0], b.s8, acc[0][t], 0, 0, 0);
            acc[1][t] = __builtin_amdgcn_mfma_f32_16x16x32_bf16(afr[1], b.s8, acc[1][t], 0, 0, 0);
        }
    }

    float bsv[7];
#pragma unroll
    for (int t = 0; t < 7; t++) bsv[t] = b2s[t * 16 + cl];

#pragma unroll
    for (int m = 0; m < 2; m++) {
#pragma unroll
        for (int r = 0; r < 4; r++) {
            int row = v0 + m * 16 + gq * 4 + r;
            float lg[7];
#pragma unroll
            for (int t = 0; t < 7; t++) lg[t] = acc[m][t][r] + bsv[t];
            float mx = lg[0];
#pragma unroll
            for (int t = 1; t < 7; t++) mx = fmaxf(mx, lg[t]);
            mx = fmaxf(mx, __shfl_xor(mx, 1, 64));
            mx = fmaxf(mx, __shfl_xor(mx, 2, 64));
            mx = fmaxf(mx, __shfl_xor(mx, 4, 64));
            mx = fmaxf(mx, __shfl_xor(mx, 8, 64));
            float s = 0.f;
#pragma unroll
            for (int t = 0; t < 7; t++) s += __expf(lg[t] - mx);
            s += __shfl_xor(s, 1, 64);
            s += __shfl_xor(s, 2, 64);
            s += __shfl_xor(s, 4, 64);
            s += __shfl_xor(s, 8, 64);
            float lse = mx + __logf(s);
            if (row < N) {
#pragma unroll
                for (int t = 0; t < 7; t++) {
                    int c = t * 16 + cl;
                    if (c < 100) out[(size_t)row * 100 + c] = lg[t] - lse;
                }
            }
        }
    }
}

extern "C" void kernel_launch(void* const* d_in, const int* in_sizes, int n_in,
                              void* d_out, int out_size, void* d_ws, size_t ws_size,
                              hipStream_t stream) {
    const float* x  = (const float*)d_in[0];
    const int*   ei = (const int*)d_in[1];   // int32 (JAX x64 disabled)
    const float* W1 = (const float*)d_in[2];
    const float* b1 = (const float*)d_in[3];
    const float* W2 = (const float*)d_in[4];
    const float* b2 = (const float*)d_in[5];
    float* out = (float*)d_out;

    int N = in_sizes[0] / 512;
    int E = in_sizes[1] / 2;
    const int* srcI = ei;
    const int* dstI = ei + E;

    char* wsb = (char*)d_ws;
    size_t off = 0;
    auto alloc = [&](size_t bytes) {
        void* p = wsb + off;
        off = (off + bytes + 255) & ~(size_t)255;
        return p;
    };
    int*    cnt      = (int*)alloc((size_t)N * 4);
    int*    cursor   = (int*)alloc((size_t)N * 4);
    float*  dinv     = (float*)alloc((size_t)N * 4);
    int*    rp       = (int*)alloc((size_t)(N + 1) * 4);
    int*    partials = (int*)alloc(1024 * 4);
    ushort* w1hi     = (ushort*)alloc(8192 * 8 * 2 * 2);   // hi then lo, 262 KB
    ushort* w1lo     = w1hi + 65536;
    ushort* w2frag   = (ushort*)alloc(1792 * 8 * 2);
    float*  b2pad    = (float*)alloc(112 * 4);
    float2* colw     = (float2*)alloc((size_t)E * 8);
    uint*   h1       = (uint*)alloc((size_t)N * 64 * 4);   // bf16 x128 per row
    uint*   a1       = (uint*)alloc((size_t)N * 64 * 4);
    uint*   g2       = h1;  // h1 dead after agg1; reuse

    hipMemsetAsync(cnt, 0, (size_t)N * 4, stream);
    hipMemsetAsync(cursor, 0, (size_t)N * 4, stream);

    k_degree<<<(E + 255) / 256, 256, 0, stream>>>(dstI, E, cnt);
    k_dinv<<<(N + 255) / 256, 256, 0, stream>>>(cnt, dinv, N);
    int nb = (N + 511) / 512;
    k_scan1<<<nb, 512, 0, stream>>>(cnt, rp, partials, N);
    k_scan2<<<1, 64, 0, stream>>>(partials, nb);
    k_scan3<<<nb, 512, 0, stream>>>(rp, partials, N, E);
    k_fill<<<(E + 255) / 256, 256, 0, stream>>>(srcI, dstI, E, rp, cursor, dinv, colw);
    k_w1prep<<<32, 256, 0, stream>>>(W1, w1hi, w1lo);
    k_w2prep<<<8, 256, 0, stream>>>(W2, b2, w2frag, b2pad);

    k_gemm1<<<(N + 127) / 128, 256, 0, stream>>>(x, (const uint4*)w1hi, (const uint4*)w1lo, h1, N);
    k_agg<true><<<(N + 3) / 4, 256, 0, stream>>>(h1, dinv, rp, colw, b1, a1, N);
    k_agg<false><<<(N + 3) / 4, 256, 0, stream>>>(a1, dinv, rp, colw, nullptr, g2, N);
    k_out_mfma<<<(N + 127) / 128, 256, 0, stream>>>(g2, (const uint4*)w2frag, b2pad, out, N);
}

// Round 7
// 428.605 us; speedup vs baseline: 3.1067x; 1.0984x over previous
//
#include <hip/hip_runtime.h>
#include <math.h>

typedef __attribute__((ext_vector_type(8))) short short8;
typedef __attribute__((ext_vector_type(4))) float f32x4;
typedef _Float16 half8 __attribute__((ext_vector_type(8)));
typedef __fp16 fp16x2 __attribute__((ext_vector_type(2)));
typedef unsigned int uint;

__device__ inline uint f2bf(float f) {            // RNE float->bf16 (low 16 bits)
    uint u = __float_as_uint(f);
    return (u + 0x7fffu + ((u >> 16) & 1u)) >> 16;
}
__device__ inline uint pack2(float lo, float hi) { return f2bf(lo) | (f2bf(hi) << 16); }
__device__ inline float bflo(uint u) { return __uint_as_float(u << 16); }
__device__ inline float bfhi(uint u) { return __uint_as_float(u & 0xffff0000u); }
__device__ inline uint cvtpk(float lo, float hi) {
    uint r;
    asm("v_cvt_pk_bf16_f32 %0, %1, %2" : "=v"(r) : "v"(lo), "v"(hi));
    return r;
}
__device__ inline uint pkh(float lo, float hi) {  // 2xf32 -> packed f16 (RTZ)
    union { fp16x2 h; uint u; } c;
    c.h = __builtin_amdgcn_cvt_pkrtz(lo, hi);
    return c.u;
}

// ---------------- degree / norm ----------------
__global__ void k_degree(const int* __restrict__ dst, int E, int* __restrict__ cnt) {
    int i = blockIdx.x * 256 + threadIdx.x;
    if (i < E) atomicAdd(&cnt[dst[i]], 1);
}

__global__ void k_dinv(const int* __restrict__ cnt, float* __restrict__ dinv, int N) {
    int i = blockIdx.x * 256 + threadIdx.x;
    if (i < N) dinv[i] = rsqrtf((float)(cnt[i] + 1));  // +1 self loop
}

// ---------------- scan for CSR row_ptr ----------------
__global__ __launch_bounds__(512) void k_scan1(const int* __restrict__ cnt, int* __restrict__ rp,
                                               int* __restrict__ partials, int N) {
    __shared__ int s[512];
    int i = blockIdx.x * 512 + threadIdx.x;
    int v = (i < N) ? cnt[i] : 0;
    s[threadIdx.x] = v;
    __syncthreads();
    for (int d = 1; d < 512; d <<= 1) {
        int t = (threadIdx.x >= d) ? s[threadIdx.x - d] : 0;
        __syncthreads();
        s[threadIdx.x] += t;
        __syncthreads();
    }
    if (i < N) rp[i] = s[threadIdx.x] - v;
    if (threadIdx.x == 511) partials[blockIdx.x] = s[511];
}

__global__ void k_scan2(int* __restrict__ partials, int nb) {
    if (threadIdx.x == 0 && blockIdx.x == 0) {
        int acc = 0;
        for (int i = 0; i < nb; i++) { int v = partials[i]; partials[i] = acc; acc += v; }
    }
}

__global__ __launch_bounds__(512) void k_scan3(int* __restrict__ rp, const int* __restrict__ partials,
                                               int N, int E) {
    int i = blockIdx.x * 512 + threadIdx.x;
    if (i < N) rp[i] += partials[blockIdx.x];
    if (i == 0) rp[N] = E;
}

// edge record: (src as float-bits, dinv[src])
__global__ void k_fill(const int* __restrict__ src, const int* __restrict__ dst, int E,
                       const int* __restrict__ rp, int* __restrict__ cursor,
                       const float* __restrict__ dinv, float2* __restrict__ colw) {
    int i = blockIdx.x * 256 + threadIdx.x;
    if (i < E) {
        int d = dst[i];
        int s = src[i];
        int pos = rp[d] + atomicAdd(&cursor[d], 1);
        colw[pos] = make_float2(__int_as_float(s), dinv[s]);
    }
}

// ---------------- W1 -> fp16 B-fragments [ks(16)][t(8)][lane(64)][j(8)] ----------------
__global__ void k_w1prep(const float* __restrict__ W1, ushort* __restrict__ frag) {
    int tid = blockIdx.x * 256 + threadIdx.x;
    if (tid < 8192) {
        int ks = tid >> 9;
        int t = (tid >> 6) & 7;
        int l = tid & 63;
        int kbase = ks * 32 + (l >> 4) * 8;
        int c = t * 16 + (l & 15);
#pragma unroll
        for (int j = 0; j < 8; j++) {
            float v = W1[(size_t)(kbase + j) * 128 + c];
            union { _Float16 h; ushort u; } cv;
            cv.h = (_Float16)v;   // RNE
            frag[(size_t)tid * 8 + j] = cv.u;
        }
    }
}

// ---------------- GEMM1 (MFMA fp16): h1 = bf16(x @ W1) ----------------
// 4 waves x 32 rows = 128 rows/block; A (x) double-buffered prefetch.
__global__ __launch_bounds__(256) void k_gemm1(const float* __restrict__ x,
                                               const uint4* __restrict__ w1f,
                                               uint* __restrict__ h1, int N) {
    __shared__ uint hsp[4][32][66];   // packed bf16 pairs, pad 66 -> conflict-free
    int tid = threadIdx.x, wv = tid >> 6, l = tid & 63;
    int cl = l & 15, kg = l >> 4;
    int n0 = blockIdx.x * 128 + wv * 32;
    int r0 = n0 + cl;       if (r0 >= N) r0 = N - 1;
    int r1 = n0 + 16 + cl;  if (r1 >= N) r1 = N - 1;
    const float* xr0 = x + (size_t)r0 * 512 + kg * 8;
    const float* xr1 = x + (size_t)r1 * 512 + kg * 8;

    f32x4 acc[2][8];
#pragma unroll
    for (int m = 0; m < 2; m++)
#pragma unroll
        for (int t = 0; t < 8; t++) acc[m][t] = (f32x4){0.f, 0.f, 0.f, 0.f};

    union U { uint4 u4; half8 h8; };

    // A prefetch buffers (current in pa*, next loaded mid-iteration)
    float4 pa0[2], pa1[2];
    pa0[0] = *(const float4*)(xr0);     pa1[0] = *(const float4*)(xr0 + 4);
    pa0[1] = *(const float4*)(xr1);     pa1[1] = *(const float4*)(xr1 + 4);

    for (int ks = 0; ks < 16; ks++) {
        // pack current A
        U A[2];
#pragma unroll
        for (int m = 0; m < 2; m++) {
            A[m].u4.x = pkh(pa0[m].x, pa0[m].y);
            A[m].u4.y = pkh(pa0[m].z, pa0[m].w);
            A[m].u4.z = pkh(pa1[m].x, pa1[m].y);
            A[m].u4.w = pkh(pa1[m].z, pa1[m].w);
        }
        // issue B loads for this ks
        uint4 bq[8];
#pragma unroll
        for (int t = 0; t < 8; t++) bq[t] = w1f[(ks * 8 + t) * 64 + l];
        // prefetch next A (overlaps with MFMAs below)
        if (ks < 15) {
            pa0[0] = *(const float4*)(xr0 + (ks + 1) * 32);
            pa1[0] = *(const float4*)(xr0 + (ks + 1) * 32 + 4);
            pa0[1] = *(const float4*)(xr1 + (ks + 1) * 32);
            pa1[1] = *(const float4*)(xr1 + (ks + 1) * 32 + 4);
        }
#pragma unroll
        for (int t = 0; t < 8; t++) {
            U B;
            B.u4 = bq[t];
            acc[0][t] = __builtin_amdgcn_mfma_f32_16x16x32_f16(A[0].h8, B.h8, acc[0][t], 0, 0, 0);
            acc[1][t] = __builtin_amdgcn_mfma_f32_16x16x32_f16(A[1].h8, B.h8, acc[1][t], 0, 0, 0);
        }
    }

    // C frag (row = m*16+kg*4+r, col = t*16+cl) -> pair via shfl_xor(1) -> packed LDS (wave-private)
#pragma unroll
    for (int m = 0; m < 2; m++)
#pragma unroll
        for (int t = 0; t < 8; t++)
#pragma unroll
            for (int r = 0; r < 4; r++) {
                float mine = acc[m][t][r];
                float other = __shfl_xor(mine, 1, 64);
                if ((cl & 1) == 0)
                    hsp[wv][m * 16 + kg * 4 + r][t * 8 + (cl >> 1)] = cvtpk(mine, other);
            }
    // same-wave LDS write->read: ordered by lgkmcnt, no barrier needed
#pragma unroll
    for (int it = 0; it < 32; it++) {
        int gr = n0 + it;
        if (gr < N) h1[(size_t)gr * 64 + l] = hsp[wv][it][l];
    }
}

// ---------------- aggregation (bf16 table, fp32 accum, unroll-8 for MLP) ----------------
template <bool RELU_BIAS>
__global__ __launch_bounds__(256) void k_agg(const uint* __restrict__ h, const float* __restrict__ dinv,
                                             const int* __restrict__ rp, const float2* __restrict__ colw,
                                             const float* __restrict__ bias, uint* __restrict__ outb, int N) {
    int wave = threadIdx.x >> 6, lane = threadIdx.x & 63;
    int v = blockIdx.x * 4 + wave;
    if (v >= N) return;
    float dv = dinv[v];
    float wself = dv * dv;
    uint us = h[(size_t)v * 64 + lane];
    float acc0 = bflo(us) * wself;
    float acc1 = bfhi(us) * wself;
    int e0 = rp[v], e1 = rp[v + 1];
    int i = e0;
    for (; i + 8 <= e1; i += 8) {
        float2 q[8];
        uint u[8];
#pragma unroll
        for (int j = 0; j < 8; j++) q[j] = colw[i + j];
#pragma unroll
        for (int j = 0; j < 8; j++) u[j] = h[(size_t)__float_as_int(q[j].x) * 64 + lane];
#pragma unroll
        for (int j = 0; j < 8; j++) {
            float w = q[j].y * dv;
            acc0 = fmaf(bflo(u[j]), w, acc0);
            acc1 = fmaf(bfhi(u[j]), w, acc1);
        }
    }
    if (i + 4 <= e1) {
        float2 q[4];
        uint u[4];
#pragma unroll
        for (int j = 0; j < 4; j++) q[j] = colw[i + j];
#pragma unroll
        for (int j = 0; j < 4; j++) u[j] = h[(size_t)__float_as_int(q[j].x) * 64 + lane];
#pragma unroll
        for (int j = 0; j < 4; j++) {
            float w = q[j].y * dv;
            acc0 = fmaf(bflo(u[j]), w, acc0);
            acc1 = fmaf(bfhi(u[j]), w, acc1);
        }
        i += 4;
    }
    for (; i < e1; i++) {
        float2 q = colw[i];
        uint u = h[(size_t)__float_as_int(q.x) * 64 + lane];
        float w = q.y * dv;
        acc0 = fmaf(bflo(u), w, acc0);
        acc1 = fmaf(bfhi(u), w, acc1);
    }
    if (RELU_BIAS) {
        float2 b = *(const float2*)&bias[2 * lane];
        acc0 = fmaxf(acc0 + b.x, 0.f);
        acc1 = fmaxf(acc1 + b.y, 0.f);
    }
    outb[(size_t)v * 64 + lane] = pack2(acc0, acc1);
}

// ---------------- W2 -> bf16 B-fragment layout [q(4)][t(7)][lane(64)][j(8)], b2 padded ----------------
__global__ void k_w2prep(const float* __restrict__ W2, const float* __restrict__ b2,
                         ushort* __restrict__ frag, float* __restrict__ b2pad) {
    int tid = blockIdx.x * 256 + threadIdx.x;
    if (tid < 1792) {
        int q = tid / 448;
        int t = (tid >> 6) % 7;
        int l = tid & 63;
        int kbase = q * 32 + (l >> 4) * 8;
        int c = t * 16 + (l & 15);
#pragma unroll
        for (int j = 0; j < 8; j++) {
            float v = (c < 100) ? W2[(kbase + j) * 100 + c] : 0.f;
            frag[(size_t)tid * 8 + j] = (ushort)f2bf(v);
        }
    } else if (tid < 1792 + 112) {
        int c = tid - 1792;
        b2pad[c] = (c < 100) ? b2[c] : -1e30f;
    }
}

// ---------------- fused MFMA GEMM2 + log_softmax ----------------
__global__ __launch_bounds__(256) void k_out_mfma(const uint* __restrict__ g2u,
                                                  const uint4* __restrict__ w2fragG,
                                                  const float* __restrict__ b2pad,
                                                  float* __restrict__ out, int N) {
    __shared__ uint4 w2s[1792];
    __shared__ float b2s[112];
    int tid = threadIdx.x;
    for (int i = tid; i < 1792; i += 256) w2s[i] = w2fragG[i];
    if (tid < 112) b2s[tid] = b2pad[tid];
    __syncthreads();

    int w = tid >> 6, l = tid & 63;
    int v0 = blockIdx.x * 128 + w * 32;
    int cl = l & 15, gq = l >> 4;

    f32x4 acc[2][7];
#pragma unroll
    for (int m = 0; m < 2; m++)
#pragma unroll
        for (int t = 0; t < 7; t++) acc[m][t] = (f32x4){0.f, 0.f, 0.f, 0.f};

    union U { uint4 u4; short8 s8; };

#pragma unroll
    for (int q = 0; q < 4; q++) {
        short8 afr[2];
#pragma unroll
        for (int m = 0; m < 2; m++) {
            int rv = v0 + m * 16 + cl;
            if (rv >= N) rv = N - 1;
            U a;
            a.u4 = *(const uint4*)&g2u[(size_t)rv * 64 + q * 16 + gq * 4];
            afr[m] = a.s8;
        }
#pragma unroll
        for (int t = 0; t < 7; t++) {
            U b;
            b.u4 = w2s[(q * 7 + t) * 64 + l];
            acc[0][t] = __builtin_amdgcn_mfma_f32_16x16x32_bf16(afr[0], b.s8, acc[0][t], 0, 0, 0);
            acc[1][t] = __builtin_amdgcn_mfma_f32_16x16x32_bf16(afr[1], b.s8, acc[1][t], 0, 0, 0);
        }
    }

    float bsv[7];
#pragma unroll
    for (int t = 0; t < 7; t++) bsv[t] = b2s[t * 16 + cl];

#pragma unroll
    for (int m = 0; m < 2; m++) {
#pragma unroll
        for (int r = 0; r < 4; r++) {
            int row = v0 + m * 16 + gq * 4 + r;
            float lg[7];
#pragma unroll
            for (int t = 0; t < 7; t++) lg[t] = acc[m][t][r] + bsv[t];
            float mx = lg[0];
#pragma unroll
            for (int t = 1; t < 7; t++) mx = fmaxf(mx, lg[t]);
            mx = fmaxf(mx, __shfl_xor(mx, 1, 64));
            mx = fmaxf(mx, __shfl_xor(mx, 2, 64));
            mx = fmaxf(mx, __shfl_xor(mx, 4, 64));
            mx = fmaxf(mx, __shfl_xor(mx, 8, 64));
            float s = 0.f;
#pragma unroll
            for (int t = 0; t < 7; t++) s += __expf(lg[t] - mx);
            s += __shfl_xor(s, 1, 64);
            s += __shfl_xor(s, 2, 64);
            s += __shfl_xor(s, 4, 64);
            s += __shfl_xor(s, 8, 64);
            float lse = mx + __logf(s);
            if (row < N) {
#pragma unroll
                for (int t = 0; t < 7; t++) {
                    int c = t * 16 + cl;
                    if (c < 100) out[(size_t)row * 100 + c] = lg[t] - lse;
                }
            }
        }
    }
}

extern "C" void kernel_launch(void* const* d_in, const int* in_sizes, int n_in,
                              void* d_out, int out_size, void* d_ws, size_t ws_size,
                              hipStream_t stream) {
    const float* x  = (const float*)d_in[0];
    const int*   ei = (const int*)d_in[1];   // int32 (JAX x64 disabled)
    const float* W1 = (const float*)d_in[2];
    const float* b1 = (const float*)d_in[3];
    const float* W2 = (const float*)d_in[4];
    const float* b2 = (const float*)d_in[5];
    float* out = (float*)d_out;

    int N = in_sizes[0] / 512;
    int E = in_sizes[1] / 2;
    const int* srcI = ei;
    const int* dstI = ei + E;

    char* wsb = (char*)d_ws;
    size_t off = 0;
    auto alloc = [&](size_t bytes) {
        void* p = wsb + off;
        off = (off + bytes + 255) & ~(size_t)255;
        return p;
    };
    int*    cnt      = (int*)alloc((size_t)N * 4);
    int*    cursor   = (int*)alloc((size_t)N * 4);
    float*  dinv     = (float*)alloc((size_t)N * 4);
    int*    rp       = (int*)alloc((size_t)(N + 1) * 4);
    int*    partials = (int*)alloc(1024 * 4);
    ushort* w1f      = (ushort*)alloc(8192 * 8 * 2);   // fp16 frags, 131 KB
    ushort* w2frag   = (ushort*)alloc(1792 * 8 * 2);
    float*  b2pad    = (float*)alloc(112 * 4);
    float2* colw     = (float2*)alloc((size_t)E * 8);
    uint*   h1       = (uint*)alloc((size_t)N * 64 * 4);   // bf16 x128 per row
    uint*   a1       = (uint*)alloc((size_t)N * 64 * 4);
    uint*   g2       = h1;  // h1 dead after agg1; reuse

    hipMemsetAsync(cnt, 0, (size_t)N * 4, stream);
    hipMemsetAsync(cursor, 0, (size_t)N * 4, stream);

    k_degree<<<(E + 255) / 256, 256, 0, stream>>>(dstI, E, cnt);
    k_dinv<<<(N + 255) / 256, 256, 0, stream>>>(cnt, dinv, N);
    int nb = (N + 511) / 512;
    k_scan1<<<nb, 512, 0, stream>>>(cnt, rp, partials, N);
    k_scan2<<<1, 64, 0, stream>>>(partials, nb);
    k_scan3<<<nb, 512, 0, stream>>>(rp, partials, N, E);
    k_fill<<<(E + 255) / 256, 256, 0, stream>>>(srcI, dstI, E, rp, cursor, dinv, colw);
    k_w1prep<<<32, 256, 0, stream>>>(W1, w1f);
    k_w2prep<<<8, 256, 0, stream>>>(W2, b2, w2frag, b2pad);

    k_gemm1<<<(N + 127) / 128, 256, 0, stream>>>(x, (const uint4*)w1f, h1, N);
    k_agg<true><<<(N + 3) / 4, 256, 0, stream>>>(h1, dinv, rp, colw, b1, a1, N);
    k_agg<false><<<(N + 3) / 4, 256, 0, stream>>>(a1, dinv, rp, colw, nullptr, g2, N);
    k_out_mfma<<<(N + 127) / 128, 256, 0, stream>>>(g2, (const uint4*)w2frag, b2pad, out, N);
}

// Round 8
// 425.077 us; speedup vs baseline: 3.1325x; 1.0083x over previous
//
#include <hip/hip_runtime.h>
#include <math.h>

typedef __attribute__((ext_vector_type(8))) short short8;
typedef __attribute__((ext_vector_type(4))) float f32x4;
typedef _Float16 half8 __attribute__((ext_vector_type(8)));
typedef __fp16 fp16x2 __attribute__((ext_vector_type(2)));
typedef unsigned int uint;

__device__ inline uint f2bf(float f) {            // RNE float->bf16 (low 16 bits)
    uint u = __float_as_uint(f);
    return (u + 0x7fffu + ((u >> 16) & 1u)) >> 16;
}
__device__ inline uint pack2(float lo, float hi) { return f2bf(lo) | (f2bf(hi) << 16); }
__device__ inline float bflo(uint u) { return __uint_as_float(u << 16); }
__device__ inline float bfhi(uint u) { return __uint_as_float(u & 0xffff0000u); }
__device__ inline uint cvtpk(float lo, float hi) {
    uint r;
    asm("v_cvt_pk_bf16_f32 %0, %1, %2" : "=v"(r) : "v"(lo), "v"(hi));
    return r;
}
__device__ inline uint pkh(float lo, float hi) {  // 2xf32 -> packed f16 (RTZ)
    union { fp16x2 h; uint u; } c;
    c.h = __builtin_amdgcn_cvt_pkrtz(lo, hi);
    return c.u;
}
__device__ inline void gload16(const void* g, void* l) {  // async global->LDS, 16B/lane
    __builtin_amdgcn_global_load_lds(
        (const __attribute__((address_space(1))) void*)g,
        (__attribute__((address_space(3))) void*)l, 16, 0, 0);
}

// ---------------- degree / norm ----------------
__global__ void k_degree(const int* __restrict__ dst, int E, int* __restrict__ cnt) {
    int i = blockIdx.x * 256 + threadIdx.x;
    if (i < E) atomicAdd(&cnt[dst[i]], 1);
}

__global__ void k_dinv(const int* __restrict__ cnt, float* __restrict__ dinv, int N) {
    int i = blockIdx.x * 256 + threadIdx.x;
    if (i < N) dinv[i] = rsqrtf((float)(cnt[i] + 1));  // +1 self loop
}

// ---------------- scan for CSR row_ptr ----------------
__global__ __launch_bounds__(512) void k_scan1(const int* __restrict__ cnt, int* __restrict__ rp,
                                               int* __restrict__ partials, int N) {
    __shared__ int s[512];
    int i = blockIdx.x * 512 + threadIdx.x;
    int v = (i < N) ? cnt[i] : 0;
    s[threadIdx.x] = v;
    __syncthreads();
    for (int d = 1; d < 512; d <<= 1) {
        int t = (threadIdx.x >= d) ? s[threadIdx.x - d] : 0;
        __syncthreads();
        s[threadIdx.x] += t;
        __syncthreads();
    }
    if (i < N) rp[i] = s[threadIdx.x] - v;
    if (threadIdx.x == 511) partials[blockIdx.x] = s[511];
}

__global__ void k_scan2(int* __restrict__ partials, int nb) {
    if (threadIdx.x == 0 && blockIdx.x == 0) {
        int acc = 0;
        for (int i = 0; i < nb; i++) { int v = partials[i]; partials[i] = acc; acc += v; }
    }
}

__global__ __launch_bounds__(512) void k_scan3(int* __restrict__ rp, const int* __restrict__ partials,
                                               int N, int E) {
    int i = blockIdx.x * 512 + threadIdx.x;
    if (i < N) rp[i] += partials[blockIdx.x];
    if (i == 0) rp[N] = E;
}

// edge record: (src as float-bits, dinv[src])
__global__ void k_fill(const int* __restrict__ src, const int* __restrict__ dst, int E,
                       const int* __restrict__ rp, int* __restrict__ cursor,
                       const float* __restrict__ dinv, float2* __restrict__ colw) {
    int i = blockIdx.x * 256 + threadIdx.x;
    if (i < E) {
        int d = dst[i];
        int s = src[i];
        int pos = rp[d] + atomicAdd(&cursor[d], 1);
        colw[pos] = make_float2(__int_as_float(s), dinv[s]);
    }
}

// ---------------- W1 -> fp16 B-fragments [ks(16)][t(8)][lane(64)][j(8)] ----------------
__global__ void k_w1prep(const float* __restrict__ W1, ushort* __restrict__ frag) {
    int tid = blockIdx.x * 256 + threadIdx.x;
    if (tid < 8192) {
        int ks = tid >> 9;
        int t = (tid >> 6) & 7;
        int l = tid & 63;
        int kbase = ks * 32 + (l >> 4) * 8;
        int c = t * 16 + (l & 15);
#pragma unroll
        for (int j = 0; j < 8; j++) {
            float v = W1[(size_t)(kbase + j) * 128 + c];
            union { _Float16 h; ushort u; } cv;
            cv.h = (_Float16)v;   // RNE
            frag[(size_t)tid * 8 + j] = cv.u;
        }
    }
}

// ---------------- GEMM1 (MFMA fp16, LDS-staged streaming): h1 = bf16(x @ W1) ----------------
// 64 rows/block, 4 waves x 16 rows. K = 4 chunks of 128. Per chunk both the x-tile
// (32 KB, XOR-swizzled via pre-swizzled GLOBAL src, linear LDS dest) and the W1 tile
// (32 KB, linear) are staged with global_load_lds; compute reads only LDS -> MFMA waits
// never drain the staging queue (vmcnt only at __syncthreads chunk boundary).
__global__ __launch_bounds__(256) void k_gemm1(const float* __restrict__ x,
                                               const uint4* __restrict__ w1f,
                                               uint* __restrict__ h1, int N) {
    __shared__ char lds[131072];          // [0,64K): x dbuf, [64K,128K): B dbuf
    int tid = threadIdx.x, wv = tid >> 6, l = tid & 63;
    int cl = l & 15, kg = l >> 4;
    int row0 = blockIdx.x * 64;

    auto stage = [&](int c) {
        char* xbase = lds + (c & 1) * 32768;
        char* bbase = lds + 65536 + (c & 1) * 32768;
        const char* bsrc = (const char*)w1f + (size_t)(c * 2048) * 16;
#pragma unroll
        for (int i = 0; i < 8; i++) {
            int s = wv * 512 + i * 64 + l;          // 16B-slot index, 0..2047
            // x-tile: slot s -> (row = s>>5, kk = s&31); content = x[row][(kk^row&7)*4 ..]
            int row = s >> 5, kk = s & 31;
            int kslot = kk ^ (row & 7);
            int rg = row0 + row; if (rg >= N) rg = N - 1;
            const float* gs = x + (size_t)rg * 512 + c * 128 + kslot * 4;
            gload16(gs, xbase + (size_t)(s - l) * 16);
            // B-tile: straight linear copy
            gload16(bsrc + (size_t)s * 16, bbase + (size_t)(s - l) * 16);
        }
    };

    f32x4 acc[8];
#pragma unroll
    for (int t = 0; t < 8; t++) acc[t] = (f32x4){0.f, 0.f, 0.f, 0.f};

    union U { uint4 u4; half8 h8; };
    int rowl = wv * 16 + cl;
    int swz = cl & 7;

    stage(0);
    __syncthreads();
    for (int c = 0; c < 4; c++) {
        if (c < 3) stage(c + 1);
        const char* xbase = lds + (c & 1) * 32768;
        const char* bbase = lds + 65536 + (c & 1) * 32768;
#pragma unroll
        for (int ks = 0; ks < 4; ks++) {
            int k4 = ks * 8 + kg * 2;
            float4 a0 = *(const float4*)(xbase + (size_t)(rowl * 32 + (k4 ^ swz)) * 16);
            float4 a1 = *(const float4*)(xbase + (size_t)(rowl * 32 + ((k4 + 1) ^ swz)) * 16);
            U A;
            A.u4.x = pkh(a0.x, a0.y);
            A.u4.y = pkh(a0.z, a0.w);
            A.u4.z = pkh(a1.x, a1.y);
            A.u4.w = pkh(a1.z, a1.w);
#pragma unroll
            for (int t = 0; t < 8; t++) {
                U B;
                B.u4 = *(const uint4*)(bbase + (size_t)(((ks * 8 + t) * 64 + l)) * 16);
                acc[t] = __builtin_amdgcn_mfma_f32_16x16x32_f16(A.h8, B.h8, acc[t], 0, 0, 0);
            }
        }
        if (c < 3) __syncthreads();
    }

    // epilogue: C frag (row = kg*4+r, col = t*16+cl) -> packed bf16 rows via LDS.
    // hsp aliases x-buf half 0 (last read finished before the final barrier); per-wave region.
    uint* hsp = (uint*)lds;   // [4][16][66]
#pragma unroll
    for (int t = 0; t < 8; t++)
#pragma unroll
        for (int r = 0; r < 4; r++) {
            float mine = acc[t][r];
            float other = __shfl_xor(mine, 1, 64);
            if ((cl & 1) == 0)
                hsp[(wv * 16 + kg * 4 + r) * 66 + t * 8 + (cl >> 1)] = cvtpk(mine, other);
        }
#pragma unroll
    for (int it = 0; it < 16; it++) {
        int gr = row0 + wv * 16 + it;
        if (gr < N) h1[(size_t)gr * 64 + l] = hsp[(wv * 16 + it) * 66 + l];
    }
}

// ---------------- aggregation (bf16 table, fp32 accum, unroll-8 for MLP) ----------------
template <bool RELU_BIAS>
__global__ __launch_bounds__(256) void k_agg(const uint* __restrict__ h, const float* __restrict__ dinv,
                                             const int* __restrict__ rp, const float2* __restrict__ colw,
                                             const float* __restrict__ bias, uint* __restrict__ outb, int N) {
    int wave = threadIdx.x >> 6, lane = threadIdx.x & 63;
    int v = blockIdx.x * 4 + wave;
    if (v >= N) return;
    float dv = dinv[v];
    float wself = dv * dv;
    uint us = h[(size_t)v * 64 + lane];
    float acc0 = bflo(us) * wself;
    float acc1 = bfhi(us) * wself;
    int e0 = rp[v], e1 = rp[v + 1];
    int i = e0;
    for (; i + 8 <= e1; i += 8) {
        float2 q[8];
        uint u[8];
#pragma unroll
        for (int j = 0; j < 8; j++) q[j] = colw[i + j];
#pragma unroll
        for (int j = 0; j < 8; j++) u[j] = h[(size_t)__float_as_int(q[j].x) * 64 + lane];
#pragma unroll
        for (int j = 0; j < 8; j++) {
            float w = q[j].y * dv;
            acc0 = fmaf(bflo(u[j]), w, acc0);
            acc1 = fmaf(bfhi(u[j]), w, acc1);
        }
    }
    if (i + 4 <= e1) {
        float2 q[4];
        uint u[4];
#pragma unroll
        for (int j = 0; j < 4; j++) q[j] = colw[i + j];
#pragma unroll
        for (int j = 0; j < 4; j++) u[j] = h[(size_t)__float_as_int(q[j].x) * 64 + lane];
#pragma unroll
        for (int j = 0; j < 4; j++) {
            float w = q[j].y * dv;
            acc0 = fmaf(bflo(u[j]), w, acc0);
            acc1 = fmaf(bfhi(u[j]), w, acc1);
        }
        i += 4;
    }
    for (; i < e1; i++) {
        float2 q = colw[i];
        uint u = h[(size_t)__float_as_int(q.x) * 64 + lane];
        float w = q.y * dv;
        acc0 = fmaf(bflo(u), w, acc0);
        acc1 = fmaf(bfhi(u), w, acc1);
    }
    if (RELU_BIAS) {
        float2 b = *(const float2*)&bias[2 * lane];
        acc0 = fmaxf(acc0 + b.x, 0.f);
        acc1 = fmaxf(acc1 + b.y, 0.f);
    }
    outb[(size_t)v * 64 + lane] = pack2(acc0, acc1);
}

// ---------------- W2 -> bf16 B-fragment layout [q(4)][t(7)][lane(64)][j(8)], b2 padded ----------------
__global__ void k_w2prep(const float* __restrict__ W2, const float* __restrict__ b2,
                         ushort* __restrict__ frag, float* __restrict__ b2pad) {
    int tid = blockIdx.x * 256 + threadIdx.x;
    if (tid < 1792) {
        int q = tid / 448;
        int t = (tid >> 6) % 7;
        int l = tid & 63;
        int kbase = q * 32 + (l >> 4) * 8;
        int c = t * 16 + (l & 15);
#pragma unroll
        for (int j = 0; j < 8; j++) {
            float v = (c < 100) ? W2[(kbase + j) * 100 + c] : 0.f;
            frag[(size_t)tid * 8 + j] = (ushort)f2bf(v);
        }
    } else if (tid < 1792 + 112) {
        int c = tid - 1792;
        b2pad[c] = (c < 100) ? b2[c] : -1e30f;
    }
}

// ---------------- fused MFMA GEMM2 + log_softmax ----------------
__global__ __launch_bounds__(256) void k_out_mfma(const uint* __restrict__ g2u,
                                                  const uint4* __restrict__ w2fragG,
                                                  const float* __restrict__ b2pad,
                                                  float* __restrict__ out, int N) {
    __shared__ uint4 w2s[1792];
    __shared__ float b2s[112];
    int tid = threadIdx.x;
    for (int i = tid; i < 1792; i += 256) w2s[i] = w2fragG[i];
    if (tid < 112) b2s[tid] = b2pad[tid];
    __syncthreads();

    int w = tid >> 6, l = tid & 63;
    int v0 = blockIdx.x * 128 + w * 32;
    int cl = l & 15, gq = l >> 4;

    f32x4 acc[2][7];
#pragma unroll
    for (int m = 0; m < 2; m++)
#pragma unroll
        for (int t = 0; t < 7; t++) acc[m][t] = (f32x4){0.f, 0.f, 0.f, 0.f};

    union U { uint4 u4; short8 s8; };

#pragma unroll
    for (int q = 0; q < 4; q++) {
        short8 afr[2];
#pragma unroll
        for (int m = 0; m < 2; m++) {
            int rv = v0 + m * 16 + cl;
            if (rv >= N) rv = N - 1;
            U a;
            a.u4 = *(const uint4*)&g2u[(size_t)rv * 64 + q * 16 + gq * 4];
            afr[m] = a.s8;
        }
#pragma unroll
        for (int t = 0; t < 7; t++) {
            U b;
            b.u4 = w2s[(q * 7 + t) * 64 + l];
            acc[0][t] = __builtin_amdgcn_mfma_f32_16x16x32_bf16(afr[0], b.s8, acc[0][t], 0, 0, 0);
            acc[1][t] = __builtin_amdgcn_mfma_f32_16x16x32_bf16(afr[1], b.s8, acc[1][t], 0, 0, 0);
        }
    }

    float bsv[7];
#pragma unroll
    for (int t = 0; t < 7; t++) bsv[t] = b2s[t * 16 + cl];

#pragma unroll
    for (int m = 0; m < 2; m++) {
#pragma unroll
        for (int r = 0; r < 4; r++) {
            int row = v0 + m * 16 + gq * 4 + r;
            float lg[7];
#pragma unroll
            for (int t = 0; t < 7; t++) lg[t] = acc[m][t][r] + bsv[t];
            float mx = lg[0];
#pragma unroll
            for (int t = 1; t < 7; t++) mx = fmaxf(mx, lg[t]);
            mx = fmaxf(mx, __shfl_xor(mx, 1, 64));
            mx = fmaxf(mx, __shfl_xor(mx, 2, 64));
            mx = fmaxf(mx, __shfl_xor(mx, 4, 64));
            mx = fmaxf(mx, __shfl_xor(mx, 8, 64));
            float s = 0.f;
#pragma unroll
            for (int t = 0; t < 7; t++) s += __expf(lg[t] - mx);
            s += __shfl_xor(s, 1, 64);
            s += __shfl_xor(s, 2, 64);
            s += __shfl_xor(s, 4, 64);
            s += __shfl_xor(s, 8, 64);
            float lse = mx + __logf(s);
            if (row < N) {
#pragma unroll
                for (int t = 0; t < 7; t++) {
                    int c = t * 16 + cl;
                    if (c < 100) out[(size_t)row * 100 + c] = lg[t] - lse;
                }
            }
        }
    }
}

extern "C" void kernel_launch(void* const* d_in, const int* in_sizes, int n_in,
                              void* d_out, int out_size, void* d_ws, size_t ws_size,
                              hipStream_t stream) {
    const float* x  = (const float*)d_in[0];
    const int*   ei = (const int*)d_in[1];   // int32 (JAX x64 disabled)
    const float* W1 = (const float*)d_in[2];
    const float* b1 = (const float*)d_in[3];
    const float* W2 = (const float*)d_in[4];
    const float* b2 = (const float*)d_in[5];
    float* out = (float*)d_out;

    int N = in_sizes[0] / 512;
    int E = in_sizes[1] / 2;
    const int* srcI = ei;
    const int* dstI = ei + E;

    char* wsb = (char*)d_ws;
    size_t off = 0;
    auto alloc = [&](size_t bytes) {
        void* p = wsb + off;
        off = (off + bytes + 255) & ~(size_t)255;
        return p;
    };
    int*    cnt      = (int*)alloc((size_t)N * 4);
    int*    cursor   = (int*)alloc((size_t)N * 4);
    float*  dinv     = (float*)alloc((size_t)N * 4);
    int*    rp       = (int*)alloc((size_t)(N + 1) * 4);
    int*    partials = (int*)alloc(1024 * 4);
    ushort* w1f      = (ushort*)alloc(8192 * 8 * 2);   // fp16 frags, 131 KB
    ushort* w2frag   = (ushort*)alloc(1792 * 8 * 2);
    float*  b2pad    = (float*)alloc(112 * 4);
    float2* colw     = (float2*)alloc((size_t)E * 8);
    uint*   h1       = (uint*)alloc((size_t)N * 64 * 4);   // bf16 x128 per row
    uint*   a1       = (uint*)alloc((size_t)N * 64 * 4);
    uint*   g2       = h1;  // h1 dead after agg1; reuse

    hipMemsetAsync(cnt, 0, (size_t)N * 4, stream);
    hipMemsetAsync(cursor, 0, (size_t)N * 4, stream);

    k_degree<<<(E + 255) / 256, 256, 0, stream>>>(dstI, E, cnt);
    k_dinv<<<(N + 255) / 256, 256, 0, stream>>>(cnt, dinv, N);
    int nb = (N + 511) / 512;
    k_scan1<<<nb, 512, 0, stream>>>(cnt, rp, partials, N);
    k_scan2<<<1, 64, 0, stream>>>(partials, nb);
    k_scan3<<<nb, 512, 0, stream>>>(rp, partials, N, E);
    k_fill<<<(E + 255) / 256, 256, 0, stream>>>(srcI, dstI, E, rp, cursor, dinv, colw);
    k_w1prep<<<32, 256, 0, stream>>>(W1, w1f);
    k_w2prep<<<8, 256, 0, stream>>>(W2, b2, w2frag, b2pad);

    k_gemm1<<<(N + 63) / 64, 256, 0, stream>>>(x, (const uint4*)w1f, h1, N);
    k_agg<true><<<(N + 3) / 4, 256, 0, stream>>>(h1, dinv, rp, colw, b1, a1, N);
    k_agg<false><<<(N + 3) / 4, 256, 0, stream>>>(a1, dinv, rp, colw, nullptr, g2, N);
    k_out_mfma<<<(N + 127) / 128, 256, 0, stream>>>(g2, (const uint4*)w2frag, b2pad, out, N);
}